// Round 1
// baseline (657.368 us; speedup 1.0000x reference)
//
#include <hip/hip_runtime.h>
#include <hip/hip_fp16.h>

// ImplicitPointHead fused kernel (MI355X / gfx950)
// 128 instances x (own MLP weights) x 2048 points.
//   x0 = concat(PE(coords), features)  [512 ch x 2048 pts]
//   L0: 256x512 +b, relu; L1/L2: 256x256 +b, relu; L3: 1x256 +b
// Strategy: one block = (instance, 128-point tile). Activations point-major in
// LDS (f16), layers computed as y^T = x^T * w^T with mfma_f32_16x16x32_f16 so
// every layer's output layout == input layout (in-place chaining).

#define NI      128
#define NPTS    2048
#define CH      256
#define NPARAM  263169
#define PT      128
#define NTILES  (NPTS / PT)     // 16
#define ROWS    536             // f16 per LDS row (512 + 24 pad) -> 1072 B row
                                // 1072 B = 268 dw == 12 mod 32 banks: 2-way (free), 16B aligned

#define WOFF0   0
#define WOFF1   131072
#define WOFF2   196608
#define WOFF3   262144
#define BOFF0   262400
#define BOFF1   262656
#define BOFF2   262912
#define BOFF3   263168

typedef _Float16 f16x8 __attribute__((ext_vector_type(8)));
typedef float    f32x4 __attribute__((ext_vector_type(4)));

__global__ __launch_bounds__(512, 2) void iph_fused(
    const float* __restrict__ feat,     // [128][256][2048]
    const float* __restrict__ coords,   // [128][2048][2]
    const float* __restrict__ params,   // [128][263169]
    const float* __restrict__ peg,      // [2][128]
    float* __restrict__ out)            // [128][1][2048]
{
    __shared__ _Float16 X[PT * ROWS];

    const int bid  = blockIdx.x;
    // XCD swizzle: all 16 tiles of an instance share one XCD's L2 (weights ~1MB/inst)
    const int inst = (bid & 7) | ((bid >> 7) << 3);
    const int tile = (bid >> 3) & 15;
    const int p0   = tile * PT;
    const int tid  = threadIdx.x;
    const float* __restrict__ P = params + (size_t)inst * NPARAM;

    // ---- Phase A: positional encoding -> X[pt][0..255]
    {
        const int pt   = tid >> 2;     // 0..127
        const int part = tid & 3;      // 32 freqs each
        const float cx = coords[((size_t)inst * NPTS + p0 + pt) * 2 + 0];
        const float cy = coords[((size_t)inst * NPTS + p0 + pt) * 2 + 1];
        const float a = 2.f * cx - 1.f;
        const float b = 2.f * cy - 1.f;
        #pragma unroll
        for (int j = 0; j < 32; ++j) {
            const int f = part * 32 + j;
            float locr = a * peg[f] + b * peg[128 + f];   // pre-2pi value
            locr -= floorf(locr);                          // period-1 reduction
            const float s = __builtin_amdgcn_sinf(locr);   // sin(2*pi*locr)
            const float c = __builtin_amdgcn_cosf(locr);
            X[pt * ROWS + f]       = (_Float16)s;
            X[pt * ROWS + 128 + f] = (_Float16)c;
        }
    }
    // ---- Phase A2: features -> X[pt][256..511] (coalesced global, b16 LDS scatter)
    {
        #pragma unroll 4
        for (int it = 0; it < 64; ++it) {
            const int idx = it * 512 + tid;   // 0..32767
            const int c = idx >> 7;           // 0..255
            const int p = idx & 127;
            const float v = feat[((size_t)inst * CH + c) * NPTS + p0 + p];
            X[p * ROWS + 256 + c] = (_Float16)v;
        }
    }
    __syncthreads();

    const int lane = tid & 63;
    const int wave = tid >> 6;
    const int l15  = lane & 15;
    const int hi   = lane >> 4;
    const int wm   = wave >> 2;   // 0..1 : points
    const int wn   = wave & 3;    // 0..3 : out-channels

    // One hidden layer: reads X[pt][0..K-1], writes relu(w@x+b) to X[pt][0..255]
    auto run_layer = [&](const int woff, const int boff, const int K) {
        f32x4 acc[4][4];
        #pragma unroll
        for (int mt = 0; mt < 4; ++mt)
            #pragma unroll
            for (int nt = 0; nt < 4; ++nt)
                acc[mt][nt] = (f32x4){0.f, 0.f, 0.f, 0.f};

        const int nks = K >> 5;
        for (int ks = 0; ks < nks; ++ks) {
            f16x8 afrag[4];
            #pragma unroll
            for (int mt = 0; mt < 4; ++mt) {
                const int pt = wm * 64 + mt * 16 + l15;
                afrag[mt] = *(const f16x8*)&X[pt * ROWS + ks * 32 + hi * 8];
            }
            f16x8 bfrag[4];
            #pragma unroll
            for (int nt = 0; nt < 4; ++nt) {
                const int co = wn * 64 + nt * 16 + l15;
                const float* wp = P + woff + (size_t)co * K + ks * 32 + hi * 8;
                float w8[8];
                __builtin_memcpy(w8, wp, 32);   // 4B-aligned ok on gfx950
                f16x8 bb;
                #pragma unroll
                for (int j = 0; j < 8; ++j) bb[j] = (_Float16)w8[j];
                bfrag[nt] = bb;
            }
            #pragma unroll
            for (int mt = 0; mt < 4; ++mt)
                #pragma unroll
                for (int nt = 0; nt < 4; ++nt)
                    acc[mt][nt] = __builtin_amdgcn_mfma_f32_16x16x32_f16(
                        afrag[mt], bfrag[nt], acc[mt][nt], 0, 0, 0);
        }

        float bias[4];
        #pragma unroll
        for (int nt = 0; nt < 4; ++nt)
            bias[nt] = P[boff + wn * 64 + nt * 16 + l15];

        __syncthreads();   // all waves done reading X
        #pragma unroll
        for (int mt = 0; mt < 4; ++mt) {
            #pragma unroll
            for (int nt = 0; nt < 4; ++nt) {
                #pragma unroll
                for (int r = 0; r < 4; ++r) {
                    float v = acc[mt][nt][r] + bias[nt];
                    v = fmaxf(v, 0.f);
                    // C/D layout (m89): col = lane&15, row = (lane>>4)*4 + reg
                    const int pt = wm * 64 + mt * 16 + hi * 4 + r;
                    const int ch = wn * 64 + nt * 16 + l15;
                    X[pt * ROWS + ch] = (_Float16)v;
                }
            }
        }
        __syncthreads();
    };

    run_layer(WOFF0, BOFF0, 512);
    run_layer(WOFF1, BOFF1, 256);
    run_layer(WOFF2, BOFF2, 256);

    // ---- Final layer: out[pt] = w3 . act3[pt] + b3
    if (tid < PT) {
        const int pt = tid;
        float sum = P[BOFF3];
        const f16x8* row = (const f16x8*)&X[pt * ROWS];
        #pragma unroll 8
        for (int j = 0; j < 32; ++j) {
            const f16x8 v = row[j];
            const float* wp = P + WOFF3 + j * 8;
            float w8[8];
            __builtin_memcpy(w8, wp, 32);
            sum += (float)v[0]*w8[0] + (float)v[1]*w8[1] + (float)v[2]*w8[2] + (float)v[3]*w8[3]
                 + (float)v[4]*w8[4] + (float)v[5]*w8[5] + (float)v[6]*w8[6] + (float)v[7]*w8[7];
        }
        out[(size_t)inst * NPTS + p0 + pt] = sum;
    }
}

extern "C" void kernel_launch(void* const* d_in, const int* in_sizes, int n_in,
                              void* d_out, int out_size, void* d_ws, size_t ws_size,
                              hipStream_t stream) {
    (void)in_sizes; (void)n_in; (void)d_ws; (void)ws_size; (void)out_size;
    const float* feat   = (const float*)d_in[0];
    const float* coords = (const float*)d_in[1];
    const float* params = (const float*)d_in[2];
    const float* peg    = (const float*)d_in[3];
    float* out = (float*)d_out;

    dim3 grid(NI * NTILES);   // 2048 blocks
    dim3 block(512);
    iph_fused<<<grid, block, 0, stream>>>(feat, coords, params, peg, out);
}

// Round 2
// 259.641 us; speedup vs baseline: 2.5318x; 2.5318x over previous
//
#include <hip/hip_runtime.h>
#include <hip/hip_fp16.h>

// ImplicitPointHead fused (MI355X / gfx950) — round 2
// Changes vs r1: (a) prep kernel pre-converts weights fp32->fp16 into d_ws in
// MFMA-fragment order -> B-frag load is one coalesced dwordx4/lane, no cvt;
// (b) PT 128->64 (LDS 68.6 KB) -> 2 blocks/CU, 4 waves/SIMD.

#define NI      128
#define NPTS    2048
#define CH      256
#define NPARAM  263169
#define PT      64
#define NTILES  (NPTS / PT)     // 32
#define ROWS    536             // f16 per LDS row (512+24 pad); 1072 B, 16B-aligned

#define WOFF0   0
#define WOFF1   131072
#define WOFF2   196608
#define WOFF3   262144
#define BOFF0   262400
#define BOFF1   262656
#define BOFF2   262912
#define BOFF3   263168

// fragment-layout f16 weight cache in d_ws (per instance, f16 offsets)
#define PI_L0   0        // 16 ks * 16 cb * 64 lane * 8  = 131072
#define PI_L1   131072   // 8*16*64*8 = 65536
#define PI_L2   196608
#define PI_L3   262144   // 256 (layer-3 weight vector)
#define WS_PER_INST 262400
#define WS_BYTES ((size_t)NI * WS_PER_INST * 2)

typedef _Float16 f16x8 __attribute__((ext_vector_type(8)));
typedef float    f32x4 __attribute__((ext_vector_type(4)));

// ---------------- prep: params fp32 -> fragment-ordered fp16 ----------------
__global__ __launch_bounds__(256) void iph_prep(
    const float* __restrict__ params, _Float16* __restrict__ wsw)
{
    const int inst = blockIdx.y;
    const int r = blockIdx.x * 256 + threadIdx.x;   // 0..32799 used
    if (r >= 32800) return;
    const float* __restrict__ P = params + (size_t)inst * NPARAM;
    _Float16* __restrict__ W = wsw + (size_t)inst * WS_PER_INST;

    int rl, woff, K, dst;
    if (r < 16384)      { rl = r;         woff = WOFF0; K = 512; dst = PI_L0; }
    else if (r < 24576) { rl = r - 16384; woff = WOFF1; K = 256; dst = PI_L1; }
    else if (r < 32768) { rl = r - 24576; woff = WOFF2; K = 256; dst = PI_L2; }
    else {
        const int e = (r - 32768) * 8;   // layer-3 weights, linear
        f16x8 v;
        #pragma unroll
        for (int j = 0; j < 8; ++j) v[j] = (_Float16)P[WOFF3 + e + j];
        *(f16x8*)&W[PI_L3 + e] = v;
        return;
    }
    // frag element e = ((ks*16 + cb)*64 + lane)*8 ; lane l: co=cb*16+(l&15),
    // k = ks*32 + (l>>4)*8  (matches mfma_f32_16x16x32_f16 B-operand mapping)
    const int e    = rl * 8;
    const int lane = rl & 63;
    const int cb   = (rl >> 6) & 15;
    const int ks   = rl >> 10;
    const int co   = cb * 16 + (lane & 15);
    const int k    = ks * 32 + (lane >> 4) * 8;
    const float* __restrict__ src = P + woff + co * K + k;
    f16x8 v;
    #pragma unroll
    for (int j = 0; j < 8; ++j) v[j] = (_Float16)src[j];
    *(f16x8*)&W[dst + e] = v;
}

// ---------------- main fused kernel ----------------
template<bool PREPPED>
__global__ __launch_bounds__(512, 4) void iph_main(
    const float* __restrict__ feat,     // [128][256][2048]
    const float* __restrict__ coords,   // [128][2048][2]
    const float* __restrict__ params,   // [128][263169]
    const _Float16* __restrict__ wsw,   // fragment-ordered f16 weights
    const float* __restrict__ peg,      // [2][128]
    float* __restrict__ out)            // [128][1][2048]
{
    __shared__ _Float16 X[PT * ROWS];   // 68608 B -> 2 blocks/CU

    const int bid  = blockIdx.x;
    // all 32 tiles of an instance on one XCD (weights ~0.5MB fp16 <-> 4MB L2)
    const int inst = (bid & 7) | ((bid >> 8) << 3);
    const int tile = (bid >> 3) & 31;
    const int p0   = tile * PT;
    const int tid  = threadIdx.x;
    const float* __restrict__ P = params + (size_t)inst * NPARAM;
    const _Float16* __restrict__ WI = wsw + (size_t)inst * WS_PER_INST;

    // ---- positional encoding -> X[pt][0..255]
    {
        const int pt   = tid >> 3;     // 64 pts
        const int part = tid & 7;      // 16 freqs each
        const float cx = coords[((size_t)inst * NPTS + p0 + pt) * 2 + 0];
        const float cy = coords[((size_t)inst * NPTS + p0 + pt) * 2 + 1];
        const float a = 2.f * cx - 1.f;
        const float b = 2.f * cy - 1.f;
        #pragma unroll
        for (int j = 0; j < 16; ++j) {
            const int f = part * 16 + j;
            float locr = a * peg[f] + b * peg[128 + f];
            locr -= floorf(locr);                        // period-1 reduction
            const float s = __builtin_amdgcn_sinf(locr); // sin(2*pi*x)
            const float c = __builtin_amdgcn_cosf(locr);
            X[pt * ROWS + f]       = (_Float16)s;
            X[pt * ROWS + 128 + f] = (_Float16)c;
        }
    }
    // ---- features -> X[pt][256..511] (coalesced read; one wave = one c-row)
    {
        #pragma unroll 4
        for (int it = 0; it < 32; ++it) {
            const int idx = it * 512 + tid;   // 0..16383
            const int c = idx >> 6;           // 0..255
            const int p = idx & 63;
            const float v = feat[((size_t)inst * CH + c) * NPTS + p0 + p];
            X[p * ROWS + 256 + c] = (_Float16)v;
        }
    }
    __syncthreads();

    const int lane = tid & 63;
    const int wave = tid >> 6;     // 8 waves, each owns 32 out-channels
    const int l15  = lane & 15;
    const int hi   = lane >> 4;

    // one hidden layer: y = relu(w @ x + b), in-place on X
    auto run_layer = [&](const int foff, const int woff, const int boff, const int K) {
        f32x4 acc[4][2];
        #pragma unroll
        for (int mt = 0; mt < 4; ++mt)
            #pragma unroll
            for (int nt = 0; nt < 2; ++nt)
                acc[mt][nt] = (f32x4){0.f, 0.f, 0.f, 0.f};

        const int nks = K >> 5;
        for (int ks = 0; ks < nks; ++ks) {
            f16x8 bfrag[2];
            #pragma unroll
            for (int nt = 0; nt < 2; ++nt) {
                if (PREPPED) {
                    const int cb = wave * 2 + nt;
                    bfrag[nt] = *(const f16x8*)&WI[foff + (((ks * 16 + cb) * 64 + lane) << 3)];
                } else {
                    const int co = wave * 32 + nt * 16 + l15;
                    const float* wp = P + woff + (size_t)co * K + ks * 32 + hi * 8;
                    float w8[8];
                    __builtin_memcpy(w8, wp, 32);
                    f16x8 bb;
                    #pragma unroll
                    for (int j = 0; j < 8; ++j) bb[j] = (_Float16)w8[j];
                    bfrag[nt] = bb;
                }
            }
            f16x8 afrag[4];
            #pragma unroll
            for (int mt = 0; mt < 4; ++mt) {
                const int pt = mt * 16 + l15;
                afrag[mt] = *(const f16x8*)&X[pt * ROWS + ks * 32 + hi * 8];
            }
            #pragma unroll
            for (int mt = 0; mt < 4; ++mt)
                #pragma unroll
                for (int nt = 0; nt < 2; ++nt)
                    acc[mt][nt] = __builtin_amdgcn_mfma_f32_16x16x32_f16(
                        afrag[mt], bfrag[nt], acc[mt][nt], 0, 0, 0);
        }

        float bias[2];
        #pragma unroll
        for (int nt = 0; nt < 2; ++nt)
            bias[nt] = P[boff + wave * 32 + nt * 16 + l15];

        __syncthreads();   // all waves done reading X
        #pragma unroll
        for (int mt = 0; mt < 4; ++mt) {
            #pragma unroll
            for (int nt = 0; nt < 2; ++nt) {
                #pragma unroll
                for (int r = 0; r < 4; ++r) {
                    float v = acc[mt][nt][r] + bias[nt];
                    v = fmaxf(v, 0.f);
                    // C/D layout (m89): col = lane&15, row = (lane>>4)*4 + reg
                    const int pt = mt * 16 + hi * 4 + r;
                    const int ch = wave * 32 + nt * 16 + l15;
                    X[pt * ROWS + ch] = (_Float16)v;
                }
            }
        }
        __syncthreads();
    };

    run_layer(PI_L0, WOFF0, BOFF0, 512);
    run_layer(PI_L1, WOFF1, BOFF1, 256);
    run_layer(PI_L2, WOFF2, BOFF2, 256);

    // ---- final layer: out[pt] = w3 . act3[pt] + b3   (one wave)
    if (tid < PT) {
        const int pt = tid;
        float sum = P[BOFF3];
        const f16x8* row = (const f16x8*)&X[pt * ROWS];
        if (PREPPED) {
            #pragma unroll 8
            for (int j = 0; j < 32; ++j) {
                const f16x8 v = row[j];
                const f16x8 w = *(const f16x8*)&WI[PI_L3 + j * 8];
                #pragma unroll
                for (int q = 0; q < 8; ++q) sum += (float)v[q] * (float)w[q];
            }
        } else {
            #pragma unroll 8
            for (int j = 0; j < 32; ++j) {
                const f16x8 v = row[j];
                const float* wp = P + WOFF3 + j * 8;
                float w8[8];
                __builtin_memcpy(w8, wp, 32);
                #pragma unroll
                for (int q = 0; q < 8; ++q) sum += (float)v[q] * w8[q];
            }
        }
        out[(size_t)inst * NPTS + p0 + pt] = sum;
    }
}

extern "C" void kernel_launch(void* const* d_in, const int* in_sizes, int n_in,
                              void* d_out, int out_size, void* d_ws, size_t ws_size,
                              hipStream_t stream) {
    (void)in_sizes; (void)n_in; (void)out_size;
    const float* feat   = (const float*)d_in[0];
    const float* coords = (const float*)d_in[1];
    const float* params = (const float*)d_in[2];
    const float* peg    = (const float*)d_in[3];
    float* out = (float*)d_out;

    dim3 grid(NI * NTILES);   // 4096 blocks
    dim3 block(512);

    if (ws_size >= WS_BYTES) {
        _Float16* wsw = (_Float16*)d_ws;
        iph_prep<<<dim3(129, 128), dim3(256), 0, stream>>>(params, wsw);
        iph_main<true><<<grid, block, 0, stream>>>(feat, coords, params, wsw, peg, out);
    } else {
        iph_main<false><<<grid, block, 0, stream>>>(feat, coords, params,
                                                    (const _Float16*)d_ws, peg, out);
    }
}

// Round 4
// 242.899 us; speedup vs baseline: 2.7063x; 1.0689x over previous
//
#include <hip/hip_runtime.h>
#include <hip/hip_fp16.h>

// ImplicitPointHead fused (MI355X / gfx950) — round 4 (r3 + compile fix)
// r3 theory: kill LDS bank conflicts (2.4e7 cyc ≈ 16% of runtime) by widening
// all LDS writes: feature/PE staging via ds_write_b128 (conflict-free at odd
// 67-chunk row stride), epilogue via even/odd-interleaved B-frag channel
// mapping -> cvt_pkrtz half2 ds_write_b32 (within-row, 2-way = free).
// Final layer parallelized across all 512 threads.
// Fix vs r3: cvt_pkrtz returns __fp16-based vec2; use __fp16 vector types.

#define NI      128
#define NPTS    2048
#define CH      256
#define NPARAM  263169
#define PT      64
#define NTILES  (NPTS / PT)     // 32
#define ROWS    536             // 67 chunks of 16B per row (odd -> b128 conflict-free)

#define WOFF0   0
#define WOFF1   131072
#define WOFF2   196608
#define WOFF3   262144
#define BOFF0   262400
#define BOFF1   262656
#define BOFF2   262912
#define BOFF3   263168

// fragment-layout f16 weight cache in d_ws (per instance, f16 offsets)
#define PI_L0   0        // 16 ks * 16 cb * 64 lane * 8
#define PI_L1   131072
#define PI_L2   196608
#define PI_L3   262144
#define WS_PER_INST 262400
#define WS_BYTES ((size_t)NI * WS_PER_INST * 2)

typedef __fp16   h16x2 __attribute__((ext_vector_type(2)));
typedef _Float16 f16x8 __attribute__((ext_vector_type(8)));
typedef float    f32x4 __attribute__((ext_vector_type(4)));

union pack8 { h16x2 h[4]; f16x8 v; };

// ---------------- prep: params fp32 -> fragment-ordered fp16 ----------------
// Frag cb, lane l covers ch co = (cb>>1)*32 + 2*(l&15) + (cb&1)  [even/odd
// interleave so the main epilogue can pack adjacent channels into half2],
// k = ks*32 + (l>>4)*8.
__global__ __launch_bounds__(256) void iph_prep(
    const float* __restrict__ params, _Float16* __restrict__ wsw)
{
    const int inst = blockIdx.y;
    const int r = blockIdx.x * 256 + threadIdx.x;
    if (r >= 32800) return;
    const float* __restrict__ P = params + (size_t)inst * NPARAM;
    _Float16* __restrict__ W = wsw + (size_t)inst * WS_PER_INST;

    int rl, woff, K, dst;
    if (r < 16384)      { rl = r;         woff = WOFF0; K = 512; dst = PI_L0; }
    else if (r < 24576) { rl = r - 16384; woff = WOFF1; K = 256; dst = PI_L1; }
    else if (r < 32768) { rl = r - 24576; woff = WOFF2; K = 256; dst = PI_L2; }
    else {
        const int e = (r - 32768) * 8;
        f16x8 v;
        #pragma unroll
        for (int j = 0; j < 8; ++j) v[j] = (_Float16)P[WOFF3 + e + j];
        *(f16x8*)&W[PI_L3 + e] = v;
        return;
    }
    const int e    = rl * 8;
    const int lane = rl & 63;
    const int cb   = (rl >> 6) & 15;
    const int ks   = rl >> 10;
    const int co   = (cb >> 1) * 32 + 2 * (lane & 15) + (cb & 1);
    const int k    = ks * 32 + (lane >> 4) * 8;
    const float* __restrict__ src = P + woff + co * K + k;
    f16x8 v;
    #pragma unroll
    for (int j = 0; j < 8; ++j) v[j] = (_Float16)src[j];
    *(f16x8*)&W[dst + e] = v;
}

// ---------------- main fused kernel ----------------
template<bool PREPPED>
__global__ __launch_bounds__(512, 4) void iph_main(
    const float* __restrict__ feat,     // [128][256][2048]
    const float* __restrict__ coords,   // [128][2048][2]
    const float* __restrict__ params,   // [128][263169]
    const _Float16* __restrict__ wsw,   // fragment-ordered f16 weights
    const float* __restrict__ peg,      // [2][128]
    float* __restrict__ out)            // [128][1][2048]
{
    __shared__ _Float16 X[PT * ROWS];   // 68608 B -> 2 blocks/CU

    const int bid  = blockIdx.x;
    const int inst = (bid & 7) | ((bid >> 8) << 3);
    const int tile = (bid >> 3) & 31;
    const int p0   = tile * PT;
    const int tid  = threadIdx.x;
    const int lane = tid & 63;
    const int wave = tid >> 6;
    const int l15  = lane & 15;
    const int hi   = lane >> 4;
    const float* __restrict__ P = params + (size_t)inst * NPARAM;
    const _Float16* __restrict__ WI = wsw + (size_t)inst * WS_PER_INST;

    // ---- positional encoding -> X[pt][0..255], b128 writes
    {
        const int pt   = tid >> 3;     // 64 pts
        const int part = tid & 7;      // 16 freqs each
        const float2 cc = *(const float2*)&coords[((size_t)inst * NPTS + p0 + pt) * 2];
        const float a = 2.f * cc.x - 1.f;
        const float b = 2.f * cc.y - 1.f;
        float sv[16], cv[16];
        #pragma unroll
        for (int j = 0; j < 16; ++j) {
            const int f = part * 16 + j;
            float locr = a * peg[f] + b * peg[128 + f];
            locr -= floorf(locr);                        // period-1 reduction
            sv[j] = __builtin_amdgcn_sinf(locr);         // sin(2*pi*x)
            cv[j] = __builtin_amdgcn_cosf(locr);
        }
        pack8 s0, s1, c0, c1;
        #pragma unroll
        for (int q = 0; q < 4; ++q) {
            s0.h[q] = __builtin_amdgcn_cvt_pkrtz(sv[2*q],     sv[2*q + 1]);
            s1.h[q] = __builtin_amdgcn_cvt_pkrtz(sv[8 + 2*q], sv[9 + 2*q]);
            c0.h[q] = __builtin_amdgcn_cvt_pkrtz(cv[2*q],     cv[2*q + 1]);
            c1.h[q] = __builtin_amdgcn_cvt_pkrtz(cv[8 + 2*q], cv[9 + 2*q]);
        }
        _Float16* base = &X[pt * ROWS + part * 16];
        *(f16x8*)(base)           = s0.v;
        *(f16x8*)(base + 8)       = s1.v;
        *(f16x8*)(base + 128)     = c0.v;
        *(f16x8*)(base + 136)     = c1.v;
    }
    // ---- features -> X[pt][256..511], 8 dword loads -> one b128 write
    {
        const float* fbase = feat + (size_t)inst * CH * NPTS + p0 + lane;
        #pragma unroll
        for (int s = 0; s < 4; ++s) {
            const int c0i = s * 64 + wave * 8;
            float w8[8];
            #pragma unroll
            for (int j = 0; j < 8; ++j)
                w8[j] = fbase[(size_t)(c0i + j) * NPTS];
            pack8 pk;
            #pragma unroll
            for (int q = 0; q < 4; ++q)
                pk.h[q] = __builtin_amdgcn_cvt_pkrtz(w8[2*q], w8[2*q + 1]);
            *(f16x8*)&X[lane * ROWS + 256 + c0i] = pk.v;
        }
    }
    __syncthreads();

    // one hidden layer: y = relu(w @ x + b), in-place on X.
    // Wave owns 32 ch as 2 frags: nt covers ch = wave*32 + 2*l15 + nt.
    auto run_layer = [&](const int foff, const int woff, const int boff, const int K) {
        f32x4 acc[4][2];
        #pragma unroll
        for (int mt = 0; mt < 4; ++mt)
            #pragma unroll
            for (int nt = 0; nt < 2; ++nt)
                acc[mt][nt] = (f32x4){0.f, 0.f, 0.f, 0.f};

        const int nks = K >> 5;
        #pragma unroll 2
        for (int ks = 0; ks < nks; ++ks) {
            f16x8 bfrag[2];
            #pragma unroll
            for (int nt = 0; nt < 2; ++nt) {
                if (PREPPED) {
                    const int cb = wave * 2 + nt;
                    bfrag[nt] = *(const f16x8*)&WI[foff + (((ks * 16 + cb) * 64 + lane) << 3)];
                } else {
                    const int co = wave * 32 + 2 * l15 + nt;
                    const float* wp = P + woff + (size_t)co * K + ks * 32 + hi * 8;
                    float w8[8];
                    __builtin_memcpy(w8, wp, 32);
                    f16x8 bb;
                    #pragma unroll
                    for (int j = 0; j < 8; ++j) bb[j] = (_Float16)w8[j];
                    bfrag[nt] = bb;
                }
            }
            f16x8 afrag[4];
            #pragma unroll
            for (int mt = 0; mt < 4; ++mt)
                afrag[mt] = *(const f16x8*)&X[(mt * 16 + l15) * ROWS + ks * 32 + hi * 8];
            #pragma unroll
            for (int mt = 0; mt < 4; ++mt)
                #pragma unroll
                for (int nt = 0; nt < 2; ++nt)
                    acc[mt][nt] = __builtin_amdgcn_mfma_f32_16x16x32_f16(
                        afrag[mt], bfrag[nt], acc[mt][nt], 0, 0, 0);
        }

        const float2 bb = *(const float2*)&P[boff + wave * 32 + 2 * l15];

        __syncthreads();   // all waves done reading X
        #pragma unroll
        for (int mt = 0; mt < 4; ++mt) {
            #pragma unroll
            for (int r = 0; r < 4; ++r) {
                // C/D layout (m89): col=lane&15, row=(lane>>4)*4+r
                const float v0 = fmaxf(acc[mt][0][r] + bb.x, 0.f);
                const float v1 = fmaxf(acc[mt][1][r] + bb.y, 0.f);
                const h16x2 e = __builtin_amdgcn_cvt_pkrtz(v0, v1);
                const int pt = mt * 16 + hi * 4 + r;
                *(h16x2*)&X[pt * ROWS + wave * 32 + 2 * l15] = e;
            }
        }
        __syncthreads();
    };

    run_layer(PI_L0, WOFF0, BOFF0, 512);
    run_layer(PI_L1, WOFF1, BOFF1, 256);
    run_layer(PI_L2, WOFF2, BOFF2, 256);

    // ---- final layer: out[pt] = w3 . act3[pt] + b3, 8 threads per point.
    // Thread part sums ch in {part*8 + q*64 + j}: stride-8 chunks, conflict-free.
    {
        const int pt   = tid >> 3;
        const int part = tid & 7;
        float sum = 0.f;
        #pragma unroll
        for (int q = 0; q < 4; ++q) {
            const f16x8 v = *(const f16x8*)&X[pt * ROWS + part * 8 + q * 64];
            if (PREPPED) {
                const f16x8 w = *(const f16x8*)&WI[PI_L3 + part * 8 + q * 64];
                #pragma unroll
                for (int j = 0; j < 8; ++j) sum += (float)v[j] * (float)w[j];
            } else {
                const float* wp = P + WOFF3 + part * 8 + q * 64;
                float w8[8];
                __builtin_memcpy(w8, wp, 32);
                #pragma unroll
                for (int j = 0; j < 8; ++j) sum += (float)v[j] * w8[j];
            }
        }
        sum += __shfl_xor(sum, 1);
        sum += __shfl_xor(sum, 2);
        sum += __shfl_xor(sum, 4);
        if (part == 0)
            out[(size_t)inst * NPTS + p0 + pt] = sum + P[BOFF3];
    }
}

extern "C" void kernel_launch(void* const* d_in, const int* in_sizes, int n_in,
                              void* d_out, int out_size, void* d_ws, size_t ws_size,
                              hipStream_t stream) {
    (void)in_sizes; (void)n_in; (void)out_size;
    const float* feat   = (const float*)d_in[0];
    const float* coords = (const float*)d_in[1];
    const float* params = (const float*)d_in[2];
    const float* peg    = (const float*)d_in[3];
    float* out = (float*)d_out;

    dim3 grid(NI * NTILES);   // 4096 blocks
    dim3 block(512);

    if (ws_size >= WS_BYTES) {
        _Float16* wsw = (_Float16*)d_ws;
        iph_prep<<<dim3(129, 128), dim3(256), 0, stream>>>(params, wsw);
        iph_main<true><<<grid, block, 0, stream>>>(feat, coords, params, wsw, peg, out);
    } else {
        iph_main<false><<<grid, block, 0, stream>>>(feat, coords, params,
                                                    (const _Float16*)d_ws, peg, out);
    }
}

// Round 5
// 217.334 us; speedup vs baseline: 3.0247x; 1.1176x over previous
//
#include <hip/hip_runtime.h>
#include <hip/hip_fp16.h>

// ImplicitPointHead fused (MI355X / gfx950) — round 5
// vs r4 (243us, MfmaUtil 24%, VGPR 52 -> latency-bound, no compiler prefetch):
//  (a) explicit SW pipeline in K-loop: B-frags (L2) prefetched 2 ks ahead,
//      A-frags (LDS) 1-2 ks ahead, named rotating registers;
//  (b) s_setprio(1) around MFMA bursts;
//  (c) L3 folded into L2 epilogue (fp32 dot from acc + shfl reduce) — removes
//      L2 X-writeback, final phase, one barrier.

#define NI      128
#define NPTS    2048
#define CH      256
#define NPARAM  263169
#define PT      64
#define NTILES  (NPTS / PT)     // 32
#define ROWS    536             // 67x16B per row (odd -> minimal b128 aliasing)

#define WOFF0   0
#define WOFF1   131072
#define WOFF2   196608
#define WOFF3   262144
#define BOFF0   262400
#define BOFF1   262656
#define BOFF2   262912
#define BOFF3   263168

// fragment-layout f16 weight cache in d_ws (per instance, f16 offsets)
#define PI_L0   0        // 16 ks * 16 cb * 64 lane * 8
#define PI_L1   131072
#define PI_L2   196608
#define PI_L3   262144
#define WS_PER_INST 262400
#define WS_BYTES ((size_t)NI * WS_PER_INST * 2)

typedef __fp16   h16x2 __attribute__((ext_vector_type(2)));
typedef _Float16 f16x8 __attribute__((ext_vector_type(8)));
typedef float    f32x4 __attribute__((ext_vector_type(4)));

union pack8 { h16x2 h[4]; f16x8 v; };

// ---------------- prep: params fp32 -> fragment-ordered fp16 ----------------
// Frag cb, lane l covers ch co = (cb>>1)*32 + 2*(l&15) + (cb&1); k = ks*32+(l>>4)*8.
__global__ __launch_bounds__(256) void iph_prep(
    const float* __restrict__ params, _Float16* __restrict__ wsw)
{
    const int inst = blockIdx.y;
    const int r = blockIdx.x * 256 + threadIdx.x;
    if (r >= 32800) return;
    const float* __restrict__ P = params + (size_t)inst * NPARAM;
    _Float16* __restrict__ W = wsw + (size_t)inst * WS_PER_INST;

    int rl, woff, K, dst;
    if (r < 16384)      { rl = r;         woff = WOFF0; K = 512; dst = PI_L0; }
    else if (r < 24576) { rl = r - 16384; woff = WOFF1; K = 256; dst = PI_L1; }
    else if (r < 32768) { rl = r - 24576; woff = WOFF2; K = 256; dst = PI_L2; }
    else {
        const int e = (r - 32768) * 8;
        f16x8 v;
        #pragma unroll
        for (int j = 0; j < 8; ++j) v[j] = (_Float16)P[WOFF3 + e + j];
        *(f16x8*)&W[PI_L3 + e] = v;
        return;
    }
    const int e    = rl * 8;
    const int lane = rl & 63;
    const int cb   = (rl >> 6) & 15;
    const int ks   = rl >> 10;
    const int co   = (cb >> 1) * 32 + 2 * (lane & 15) + (cb & 1);
    const int k    = ks * 32 + (lane >> 4) * 8;
    const float* __restrict__ src = P + woff + co * K + k;
    f16x8 v;
    #pragma unroll
    for (int j = 0; j < 8; ++j) v[j] = (_Float16)src[j];
    *(f16x8*)&W[dst + e] = v;
}

// ---------------- pipelined GEMM tile ----------------
// acc[mt][nt] over 64 pts x (wave's 32 ch). B prefetch 2 ks ahead (L2),
// A prefetch 1-2 ks ahead (LDS).
template<int NKS, bool PREPPED>
__device__ __forceinline__ void gemm_tile(
    f32x4 (&acc)[4][2],
    const _Float16* __restrict__ bsrc,   // WI + PI_Lx (fragment order)
    const float* __restrict__ pw,        // P + WOFFx (fallback)
    const _Float16* __restrict__ X,
    int lane, int wave, int l15, int hi)
{
    if constexpr (PREPPED) {
        const _Float16* bp = bsrc + ((wave * 2) * 64 + lane) * 8;
        const _Float16* ap = &X[l15 * ROWS + hi * 8];
        f16x8 a0[4], a1[4], b0[2], b1[2];
        #pragma unroll
        for (int nt = 0; nt < 2; ++nt) {
            b0[nt] = *(const f16x8*)(bp + nt * 512);
            b1[nt] = *(const f16x8*)(bp + 8192 + nt * 512);
        }
        #pragma unroll
        for (int mt = 0; mt < 4; ++mt)
            a0[mt] = *(const f16x8*)(ap + mt * 16 * ROWS);

        #pragma unroll
        for (int ks = 0; ks < NKS; ks += 2) {
            f16x8 b2[2], b3[2];
            if (ks + 2 < NKS) {          // compile-time after unroll
                #pragma unroll
                for (int nt = 0; nt < 2; ++nt)
                    b2[nt] = *(const f16x8*)(bp + (ks + 2) * 8192 + nt * 512);
            }
            #pragma unroll
            for (int mt = 0; mt < 4; ++mt)
                a1[mt] = *(const f16x8*)(ap + mt * 16 * ROWS + (ks + 1) * 32);

            __builtin_amdgcn_s_setprio(1);
            #pragma unroll
            for (int mt = 0; mt < 4; ++mt) {
                acc[mt][0] = __builtin_amdgcn_mfma_f32_16x16x32_f16(a0[mt], b0[0], acc[mt][0], 0, 0, 0);
                acc[mt][1] = __builtin_amdgcn_mfma_f32_16x16x32_f16(a0[mt], b0[1], acc[mt][1], 0, 0, 0);
            }
            __builtin_amdgcn_s_setprio(0);

            if (ks + 2 < NKS) {
                #pragma unroll
                for (int nt = 0; nt < 2; ++nt)
                    b3[nt] = *(const f16x8*)(bp + (ks + 3) * 8192 + nt * 512);
                #pragma unroll
                for (int mt = 0; mt < 4; ++mt)
                    a0[mt] = *(const f16x8*)(ap + mt * 16 * ROWS + (ks + 2) * 32);
            }

            __builtin_amdgcn_s_setprio(1);
            #pragma unroll
            for (int mt = 0; mt < 4; ++mt) {
                acc[mt][0] = __builtin_amdgcn_mfma_f32_16x16x32_f16(a1[mt], b1[0], acc[mt][0], 0, 0, 0);
                acc[mt][1] = __builtin_amdgcn_mfma_f32_16x16x32_f16(a1[mt], b1[1], acc[mt][1], 0, 0, 0);
            }
            __builtin_amdgcn_s_setprio(0);

            if (ks + 2 < NKS) {
                #pragma unroll
                for (int nt = 0; nt < 2; ++nt) { b0[nt] = b2[nt]; b1[nt] = b3[nt]; }
            }
        }
    } else {
        const int K = NKS * 32;
        for (int ks = 0; ks < NKS; ++ks) {
            f16x8 bfrag[2];
            #pragma unroll
            for (int nt = 0; nt < 2; ++nt) {
                const int co = wave * 32 + 2 * l15 + nt;
                const float* wp = pw + (size_t)co * K + ks * 32 + hi * 8;
                float w8[8];
                __builtin_memcpy(w8, wp, 32);
                f16x8 bb;
                #pragma unroll
                for (int j = 0; j < 8; ++j) bb[j] = (_Float16)w8[j];
                bfrag[nt] = bb;
            }
            f16x8 afrag[4];
            #pragma unroll
            for (int mt = 0; mt < 4; ++mt)
                afrag[mt] = *(const f16x8*)&X[(mt * 16 + l15) * ROWS + ks * 32 + hi * 8];
            #pragma unroll
            for (int mt = 0; mt < 4; ++mt)
                #pragma unroll
                for (int nt = 0; nt < 2; ++nt)
                    acc[mt][nt] = __builtin_amdgcn_mfma_f32_16x16x32_f16(
                        afrag[mt], bfrag[nt], acc[mt][nt], 0, 0, 0);
        }
    }
}

// ---------------- main fused kernel ----------------
template<bool PREPPED>
__global__ __launch_bounds__(512, 4) void iph_main(
    const float* __restrict__ feat,     // [128][256][2048]
    const float* __restrict__ coords,   // [128][2048][2]
    const float* __restrict__ params,   // [128][263169]
    const _Float16* __restrict__ wsw,   // fragment-ordered f16 weights
    const float* __restrict__ peg,      // [2][128]
    float* __restrict__ out)            // [128][1][2048]
{
    __shared__ _Float16 X[PT * ROWS];   // 68608 B
    __shared__ float    partial[8][PT]; // 2 KB -> total 70.7 KB, 2 blocks/CU

    const int bid  = blockIdx.x;
    const int inst = (bid & 7) | ((bid >> 8) << 3);
    const int tile = (bid >> 3) & 31;
    const int p0   = tile * PT;
    const int tid  = threadIdx.x;
    const int lane = tid & 63;
    const int wave = tid >> 6;
    const int l15  = lane & 15;
    const int hi   = lane >> 4;
    const float* __restrict__ P = params + (size_t)inst * NPARAM;
    const _Float16* __restrict__ WI = wsw + (size_t)inst * WS_PER_INST;

    // ---- positional encoding -> X[pt][0..255], b128 writes
    {
        const int pt   = tid >> 3;     // 64 pts
        const int part = tid & 7;      // 16 freqs each
        const float2 cc = *(const float2*)&coords[((size_t)inst * NPTS + p0 + pt) * 2];
        const float a = 2.f * cc.x - 1.f;
        const float b = 2.f * cc.y - 1.f;
        float sv[16], cv[16];
        #pragma unroll
        for (int j = 0; j < 16; ++j) {
            const int f = part * 16 + j;
            float locr = a * peg[f] + b * peg[128 + f];
            locr -= floorf(locr);                        // period-1 reduction
            sv[j] = __builtin_amdgcn_sinf(locr);         // sin(2*pi*x)
            cv[j] = __builtin_amdgcn_cosf(locr);
        }
        pack8 s0, s1, c0, c1;
        #pragma unroll
        for (int q = 0; q < 4; ++q) {
            s0.h[q] = __builtin_amdgcn_cvt_pkrtz(sv[2*q],     sv[2*q + 1]);
            s1.h[q] = __builtin_amdgcn_cvt_pkrtz(sv[8 + 2*q], sv[9 + 2*q]);
            c0.h[q] = __builtin_amdgcn_cvt_pkrtz(cv[2*q],     cv[2*q + 1]);
            c1.h[q] = __builtin_amdgcn_cvt_pkrtz(cv[8 + 2*q], cv[9 + 2*q]);
        }
        _Float16* base = &X[pt * ROWS + part * 16];
        *(f16x8*)(base)           = s0.v;
        *(f16x8*)(base + 8)       = s1.v;
        *(f16x8*)(base + 128)     = c0.v;
        *(f16x8*)(base + 136)     = c1.v;
    }
    // ---- features -> X[pt][256..511], 8 dword loads -> one b128 write
    {
        const float* fbase = feat + (size_t)inst * CH * NPTS + p0 + lane;
        #pragma unroll
        for (int s = 0; s < 4; ++s) {
            const int c0i = s * 64 + wave * 8;
            float w8[8];
            #pragma unroll
            for (int j = 0; j < 8; ++j)
                w8[j] = fbase[(size_t)(c0i + j) * NPTS];
            pack8 pk;
            #pragma unroll
            for (int q = 0; q < 4; ++q)
                pk.h[q] = __builtin_amdgcn_cvt_pkrtz(w8[2*q], w8[2*q + 1]);
            *(f16x8*)&X[lane * ROWS + 256 + c0i] = pk.v;
        }
    }
    __syncthreads();

    // hidden-layer epilogue: relu(acc+b) -> X (even/odd half2 writes)
    auto write_epilogue = [&](f32x4 (&acc)[4][2], const float2 bb) {
        #pragma unroll
        for (int mt = 0; mt < 4; ++mt) {
            #pragma unroll
            for (int r = 0; r < 4; ++r) {
                // C/D layout (m89): col=lane&15, row=(lane>>4)*4+r
                const float v0 = fmaxf(acc[mt][0][r] + bb.x, 0.f);
                const float v1 = fmaxf(acc[mt][1][r] + bb.y, 0.f);
                const h16x2 e = __builtin_amdgcn_cvt_pkrtz(v0, v1);
                const int pt = mt * 16 + hi * 4 + r;
                *(h16x2*)&X[pt * ROWS + wave * 32 + 2 * l15] = e;
            }
        }
    };

    // ---- L0
    {
        f32x4 acc[4][2];
        #pragma unroll
        for (int mt = 0; mt < 4; ++mt)
            #pragma unroll
            for (int nt = 0; nt < 2; ++nt)
                acc[mt][nt] = (f32x4){0.f, 0.f, 0.f, 0.f};
        const float2 bb = *(const float2*)&P[BOFF0 + wave * 32 + 2 * l15];
        gemm_tile<16, PREPPED>(acc, WI + PI_L0, P + WOFF0, X, lane, wave, l15, hi);
        __syncthreads();
        write_epilogue(acc, bb);
        __syncthreads();
    }
    // ---- L1
    {
        f32x4 acc[4][2];
        #pragma unroll
        for (int mt = 0; mt < 4; ++mt)
            #pragma unroll
            for (int nt = 0; nt < 2; ++nt)
                acc[mt][nt] = (f32x4){0.f, 0.f, 0.f, 0.f};
        const float2 bb = *(const float2*)&P[BOFF1 + wave * 32 + 2 * l15];
        gemm_tile<8, PREPPED>(acc, WI + PI_L1, P + WOFF1, X, lane, wave, l15, hi);
        __syncthreads();
        write_epilogue(acc, bb);
        __syncthreads();
    }
    // ---- L2 + L3 fused: partial[wave][pt] = sum_{ch in wave} w3[ch]*relu(acc+b2)
    {
        f32x4 acc[4][2];
        #pragma unroll
        for (int mt = 0; mt < 4; ++mt)
            #pragma unroll
            for (int nt = 0; nt < 2; ++nt)
                acc[mt][nt] = (f32x4){0.f, 0.f, 0.f, 0.f};
        const float2 bb = *(const float2*)&P[BOFF2 + wave * 32 + 2 * l15];
        const float2 w3 = *(const float2*)&P[WOFF3 + wave * 32 + 2 * l15];
        gemm_tile<8, PREPPED>(acc, WI + PI_L2, P + WOFF2, X, lane, wave, l15, hi);
        #pragma unroll
        for (int mt = 0; mt < 4; ++mt) {
            #pragma unroll
            for (int r = 0; r < 4; ++r) {
                const float v0 = fmaxf(acc[mt][0][r] + bb.x, 0.f);
                const float v1 = fmaxf(acc[mt][1][r] + bb.y, 0.f);
                float s = v0 * w3.x + v1 * w3.y;
                s += __shfl_xor(s, 1);
                s += __shfl_xor(s, 2);
                s += __shfl_xor(s, 4);
                s += __shfl_xor(s, 8);
                if (l15 == 0)
                    partial[wave][mt * 16 + hi * 4 + r] = s;
            }
        }
        __syncthreads();
        if (tid < PT) {
            float s = P[BOFF3];
            #pragma unroll
            for (int w = 0; w < 8; ++w) s += partial[w][tid];
            out[(size_t)inst * NPTS + p0 + tid] = s;
        }
    }
}

extern "C" void kernel_launch(void* const* d_in, const int* in_sizes, int n_in,
                              void* d_out, int out_size, void* d_ws, size_t ws_size,
                              hipStream_t stream) {
    (void)in_sizes; (void)n_in; (void)out_size;
    const float* feat   = (const float*)d_in[0];
    const float* coords = (const float*)d_in[1];
    const float* params = (const float*)d_in[2];
    const float* peg    = (const float*)d_in[3];
    float* out = (float*)d_out;

    dim3 grid(NI * NTILES);   // 4096 blocks
    dim3 block(512);

    if (ws_size >= WS_BYTES) {
        _Float16* wsw = (_Float16*)d_ws;
        iph_prep<<<dim3(129, 128), dim3(256), 0, stream>>>(params, wsw);
        iph_main<true><<<grid, block, 0, stream>>>(feat, coords, params, wsw, peg, out);
    } else {
        iph_main<false><<<grid, block, 0, stream>>>(feat, coords, params,
                                                    (const _Float16*)d_ws, peg, out);
    }
}